// Round 9
// baseline (305.635 us; speedup 1.0000x reference)
//
#include <hip/hip_runtime.h>

#define NN 50000
#define EE 800000
#define INC 512
#define HIDC 128
#define OUTC 256
#define CAP 64
#define OV_CAP 65536
#define BUILD_BLOCKS 196      // ceil(800000 / (256*16)) — measured-best build form
#define GB1 782               // ceil(NN/64)

typedef __attribute__((ext_vector_type(8))) short bf16x8;
typedef __attribute__((ext_vector_type(4))) float f32x4;

__device__ __forceinline__ short f2bf(float f) {
    unsigned u = __float_as_uint(f);
    unsigned r = u + 0x7fff + ((u >> 16) & 1);   // RNE to bf16
    return (short)(r >> 16);
}
__device__ __forceinline__ float bf2f(short s) {
    return __uint_as_float(((unsigned)(unsigned short)s) << 16);
}

// ---------------------------------------------------------------------------
// GEMM core: C[M,Nc] = A[M,K] * B[Nc,K]^T (+bias). BM=64, BN=128, BK=64.
// 256 threads = 4 waves; wave computes 32x64 (2x4 tiles of 16x16x32 MFMA).
// Verified layouts: A-frag A[m=lane&15][k=quad*8+j]; C/D col=lane&15,
// row=quad*4+reg.
template<bool IN_BF16, bool ADDBIAS, bool OUT_BF16>
__device__ __forceinline__ void gemm_core(
    const void* __restrict__ Av, const float* __restrict__ B,
    const float* __restrict__ bias, void* __restrict__ Cv,
    int M, int Nc, int K, int bx, int by,
    short As[64][72], short Bs[128][72])
{
    int tid = threadIdx.x;
    int lane = tid & 63, wave = tid >> 6;
    int row0 = bx * 64, col0 = by * 128;
    int wm = (wave & 1) * 32, wn = (wave >> 1) * 64;
    int l16 = lane & 15, quad = lane >> 4;

    f32x4 acc[2][4];
#pragma unroll
    for (int i = 0; i < 2; i++)
#pragma unroll
        for (int j = 0; j < 4; j++) acc[i][j] = {0.f, 0.f, 0.f, 0.f};

    for (int k0 = 0; k0 < K; k0 += 64) {
        // ---- stage A tile 64x64 ----
        if (IN_BF16) {
            const short* A = (const short*)Av;
#pragma unroll
            for (int w = 0; w < 2; w++) {
                int f = tid + w * 256;          // 512 x 16B slots
                int rr = f >> 3, c8 = f & 7;
                int gr = row0 + rr;
                bf16x8 v = {0, 0, 0, 0, 0, 0, 0, 0};
                if (gr < M) v = *(const bf16x8*)&A[(long)gr * K + k0 + c8 * 8];
                *(bf16x8*)&As[rr][c8 * 8] = v;
            }
        } else {
            const float* A = (const float*)Av;
#pragma unroll
            for (int w = 0; w < 4; w++) {
                int f = tid + w * 256;          // 1024 x float4 slots
                int rr = f >> 4, c4 = f & 15;
                int gr = row0 + rr;
                float4 v = make_float4(0.f, 0.f, 0.f, 0.f);
                if (gr < M) v = *(const float4*)&A[(long)gr * K + k0 + c4 * 4];
                short4 s;
                s.x = f2bf(v.x); s.y = f2bf(v.y); s.z = f2bf(v.z); s.w = f2bf(v.w);
                *(short4*)&As[rr][c4 * 4] = s;
            }
        }
        // ---- stage B tile 128x64 (fp32 -> bf16) ----
#pragma unroll
        for (int w = 0; w < 8; w++) {
            int f = tid + w * 256;              // 2048 x float4 slots
            int rr = f >> 4, c4 = f & 15;
            float4 v = *(const float4*)&B[(long)(col0 + rr) * K + k0 + c4 * 4];
            short4 s;
            s.x = f2bf(v.x); s.y = f2bf(v.y); s.z = f2bf(v.z); s.w = f2bf(v.w);
            *(short4*)&Bs[rr][c4 * 4] = s;
        }
        __syncthreads();

#pragma unroll
        for (int kk = 0; kk < 64; kk += 32) {
            bf16x8 af[2], bfr[4];
#pragma unroll
            for (int i = 0; i < 2; i++)
                af[i] = *(const bf16x8*)&As[wm + i * 16 + l16][kk + quad * 8];
#pragma unroll
            for (int j = 0; j < 4; j++)
                bfr[j] = *(const bf16x8*)&Bs[wn + j * 16 + l16][kk + quad * 8];
#pragma unroll
            for (int i = 0; i < 2; i++)
#pragma unroll
                for (int j = 0; j < 4; j++)
                    acc[i][j] = __builtin_amdgcn_mfma_f32_16x16x32_bf16(
                        af[i], bfr[j], acc[i][j], 0, 0, 0);
        }
        __syncthreads();
    }

    // ---- epilogue ----
#pragma unroll
    for (int i = 0; i < 2; i++) {
#pragma unroll
        for (int rr = 0; rr < 4; rr++) {
            int grow = row0 + wm + i * 16 + quad * 4 + rr;
            if (grow < M) {
#pragma unroll
                for (int j = 0; j < 4; j++) {
                    int gcol = col0 + wn + j * 16 + l16;
                    float v = acc[i][j][rr];
                    if (ADDBIAS) v += bias[gcol];
                    if (OUT_BF16)
                        ((short*)Cv)[(long)grow * Nc + gcol] = f2bf(v);
                    else
                        ((float*)Cv)[(long)grow * Nc + gcol] = v;
                }
            }
        }
    }
}

// ---------------------------------------------------------------------------
// Fat kernel: blocks [0,196) build dst-buckets at 16 edges/thread (measured
// best: build hides under gemm1's MFMA blocks; both alternatives regressed).
// Remaining 782 blocks: h = bf16(x @ w1^T).
__global__ __launch_bounds__(256) void fat_build_gemm1(
    const int* __restrict__ ei, int* __restrict__ cnt,
    unsigned short* __restrict__ bucket, int* __restrict__ ovcnt,
    int* __restrict__ ovlist,
    const float* __restrict__ x, const float* __restrict__ w1,
    short* __restrict__ h)
{
    __shared__ short As[64][72];
    __shared__ short Bs[128][72];

    if (blockIdx.x < BUILD_BLOCKS) {
        int t = threadIdx.x;
        long base = ((long)blockIdx.x * 256 + t) * 16;
        if (base + 16 <= EE) {
            int4 sv[4], dv[4];
#pragma unroll
            for (int q = 0; q < 4; q++) {
                sv[q] = *(const int4*)&ei[base + q * 4];
                dv[q] = *(const int4*)&ei[EE + base + q * 4];
            }
            const int* sp = (const int*)sv;
            const int* dp = (const int*)dv;
#pragma unroll
            for (int k = 0; k < 16; k++) {
                int src = sp[k], dst = dp[k];
                int pos = atomicAdd(&cnt[dst], 1);
                if (pos < CAP) bucket[(long)dst * CAP + pos] = (unsigned short)src;
                else {
                    int o = atomicAdd(ovcnt, 1);
                    if (o < OV_CAP) { ovlist[o * 2] = src; ovlist[o * 2 + 1] = dst; }
                }
            }
        } else {
            for (int k = 0; k < 16; k++) {
                long e = base + k;
                if (e < EE) {
                    int src = ei[e], dst = ei[EE + e];
                    int pos = atomicAdd(&cnt[dst], 1);
                    if (pos < CAP) bucket[(long)dst * CAP + pos] = (unsigned short)src;
                    else {
                        int o = atomicAdd(ovcnt, 1);
                        if (o < OV_CAP) { ovlist[o * 2] = src; ovlist[o * 2 + 1] = dst; }
                    }
                }
            }
        }
    } else {
        gemm_core<false, false, true>(x, w1, nullptr, h, NN, HIDC, INC,
                                      blockIdx.x - BUILD_BLOCKS, 0, As, Bs);
    }
}

// out = r2 @ w2^T + b2 (A already bf16)
__global__ __launch_bounds__(256) void gemm2_k(
    const short* __restrict__ r2, const float* __restrict__ w2,
    const float* __restrict__ b2, float* __restrict__ out)
{
    __shared__ short As[64][72];
    __shared__ short Bs[128][72];
    gemm_core<true, true, false>(r2, w2, b2, out, NN, OUTC, HIDC,
                                 blockIdx.x, blockIdx.y, As, Bs);
}

// ---------------------------------------------------------------------------
// Gather, wave-per-node: lane = (sub, c8); sub=lane>>4 handles every 4th
// edge of ONE node (no max-of-4-nodes divergence inflation), c8 = 16B column
// slice. Unrolled 16 edges/iter (4 x 1KB wave-loads in flight). Cross-sub
// reduction: 2 shfl_xor. Overflow handled inline (expected never taken).
// Block = 4 waves x 4 nodes = 16 nodes; grid 3125 (= 50000 nodes exactly).
template<bool RELU>
__global__ __launch_bounds__(256) void gather_k(
    const short* __restrict__ hsrc, const unsigned short* __restrict__ bucket,
    const int* __restrict__ cnt, const int* __restrict__ ovcnt,
    const int* __restrict__ ovlist, const float* __restrict__ bias,
    short* __restrict__ rout)
{
    int wave = threadIdx.x >> 6;
    int lane = threadIdx.x & 63;
    int sub = lane >> 4, c8 = lane & 15;

#pragma unroll
    for (int it = 0; it < 4; it++) {
        int node = blockIdx.x * 16 + wave * 4 + it;   // < NN always (3125*16=NN)
        int m0 = cnt[node];
        int m = m0 > CAP ? CAP : m0;
        const unsigned short* bk = bucket + (long)node * CAP;

        float acc[8];
#pragma unroll
        for (int k = 0; k < 8; k++) acc[k] = 0.f;

        int j = 0;
        for (; j + 16 <= m; j += 16) {
            int s0 = bk[j + sub];
            int s1 = bk[j + 4 + sub];
            int s2 = bk[j + 8 + sub];
            int s3 = bk[j + 12 + sub];
            bf16x8 v0 = *(const bf16x8*)&hsrc[((long)s0 << 7) + c8 * 8];
            bf16x8 v1 = *(const bf16x8*)&hsrc[((long)s1 << 7) + c8 * 8];
            bf16x8 v2 = *(const bf16x8*)&hsrc[((long)s2 << 7) + c8 * 8];
            bf16x8 v3 = *(const bf16x8*)&hsrc[((long)s3 << 7) + c8 * 8];
#pragma unroll
            for (int k = 0; k < 8; k++)
                acc[k] += bf2f(v0[k]) + bf2f(v1[k]) + bf2f(v2[k]) + bf2f(v3[k]);
        }
        for (; j < m; j += 4) {
            int e = j + sub;
            if (e < m) {
                int s0 = bk[e];
                bf16x8 v0 = *(const bf16x8*)&hsrc[((long)s0 << 7) + c8 * 8];
#pragma unroll
                for (int k = 0; k < 8; k++) acc[k] += bf2f(v0[k]);
            }
        }

        if (m0 > CAP && sub == 0) {   // inline overflow fixup (expected never)
            int n = *ovcnt; if (n > OV_CAP) n = OV_CAP;
            for (int i = 0; i < n; i++) {
                if (ovlist[i * 2 + 1] == node) {
                    bf16x8 v0 =
                        *(const bf16x8*)&hsrc[((long)ovlist[i * 2] << 7) + c8 * 8];
#pragma unroll
                    for (int k = 0; k < 8; k++) acc[k] += bf2f(v0[k]);
                }
            }
        }

        // reduce the 4 sub-partials (lanes xor 16, xor 32)
#pragma unroll
        for (int k = 0; k < 8; k++) {
            acc[k] += __shfl_xor(acc[k], 16);
            acc[k] += __shfl_xor(acc[k], 32);
        }

        if (sub == 0) {
            bf16x8 o;
            if (RELU) {
#pragma unroll
                for (int k = 0; k < 8; k++)
                    o[k] = f2bf(fmaxf(acc[k] + bias[c8 * 8 + k], 0.f));
            } else {
#pragma unroll
                for (int k = 0; k < 8; k++) o[k] = f2bf(acc[k]);
            }
            *(bf16x8*)&rout[((long)node << 7) + c8 * 8] = o;
        }
    }
}

extern "C" void kernel_launch(void* const* d_in, const int* in_sizes, int n_in,
                              void* d_out, int out_size, void* d_ws, size_t ws_size,
                              hipStream_t stream) {
    const float* x  = (const float*)d_in[0];
    const int*   ei = (const int*)d_in[1];
    const float* w1 = (const float*)d_in[2];
    const float* b1 = (const float*)d_in[3];
    const float* w2 = (const float*)d_in[4];
    const float* b2 = (const float*)d_in[5];
    float* out = (float*)d_out;

    char* ws = (char*)d_ws;
    size_t off = 0;
    short* h    = (short*)(ws + off); off += (size_t)NN * HIDC * 2;          // 12.8 MB
    short* r    = (short*)(ws + off); off += (size_t)NN * HIDC * 2;          // 12.8 MB
    short* r2   = (short*)(ws + off); off += (size_t)NN * HIDC * 2;          // 12.8 MB
    unsigned short* bucket = (unsigned short*)(ws + off);
    off += (size_t)NN * CAP * 2;                                             // 6.4 MB
    int* cnt    = (int*)(ws + off);   off += (size_t)NN * 4;                 // 0.2 MB
    int* ovcnt  = (int*)(ws + off);   off += 256;
    int* ovlist = (int*)(ws + off);   off += (size_t)OV_CAP * 2 * 4;         // 0.5 MB

    // zero cnt + ovcnt in one memset (contiguous)
    hipMemsetAsync(cnt, 0, (size_t)NN * 4 + 4, stream);

    dim3 blk(256);

    // build buckets (blocks 0..195) || h = bf16(x @ w1^T) (blocks 196..977)
    fat_build_gemm1<<<dim3(BUILD_BLOCKS + GB1), blk, 0, stream>>>(
        ei, cnt, bucket, ovcnt, ovlist, x, w1, h);

    // r = bf16(relu(A*h + b1)), wave-per-node, overflow inline
    gather_k<true><<<dim3(3125), blk, 0, stream>>>(
        h, bucket, cnt, ovcnt, ovlist, b1, r);

    // r2 = bf16(A*r), wave-per-node, overflow inline
    gather_k<false><<<dim3(3125), blk, 0, stream>>>(
        r, bucket, cnt, ovcnt, ovlist, nullptr, r2);

    // out = r2 @ w2^T + b2
    gemm2_k<<<dim3(GB1, 2), blk, 0, stream>>>(r2, w2, b2, out);
}